// Round 1
// baseline (357.235 us; speedup 1.0000x reference)
//
#include <hip/hip_runtime.h>

#define BB 32
#define TT 2000
#define HH 512
#define LL 256
#define THRESH 0.95f

// d_ws layout:
//   float w_self[BB*TT]   : per-step contribution to the currently-open token
//   float w_next[BB*TT]   : per-step contribution to the NEXT token (nonzero only at fires)
//   int   fire_pos[BB*LL] : time index of the l-th fire per batch
//   int   nfires[BB]      : number of fires (clamped to LL)

__global__ __launch_bounds__(256) void cif_scan_kernel(
    const float* __restrict__ alphas, const int* __restrict__ tlen,
    float* __restrict__ w_self, float* __restrict__ w_next,
    int* __restrict__ fire_pos, int* __restrict__ nfires)
{
    const int b = blockIdx.x;
    __shared__ float sa[TT];
    __shared__ double red[256];

    const float* arow = alphas + b * TT;
    double s = 0.0;
    for (int t = threadIdx.x; t < TT; t += 256) {
        float a = arow[t];
        sa[t] = a;
        s += (double)a;
    }
    red[threadIdx.x] = s;
    __syncthreads();
    for (int off = 128; off > 0; off >>= 1) {
        if (threadIdx.x < off) red[threadIdx.x] += red[threadIdx.x + off];
        __syncthreads();
    }
    // Match reference: scale = float(target) / float(sum), f32 divide, f32 mult.
    const float sumf = (float)red[0];
    const float scale = (float)tlen[b] / sumf;
    for (int t = threadIdx.x; t < TT; t += 256) sa[t] = sa[t] * scale;
    __syncthreads();

    if (threadIdx.x == 0) {
        // Bit-exact f32 replay of the reference scan (op order matters only for
        // the fire decisions; weight values tolerate ulp noise).
        float integ = 0.0f;
        int nf = 0;
        float* ws = w_self + b * TT;
        float* wn = w_next + b * TT;
        int* fp = fire_pos + b * LL;
        for (int t = 0; t < TT; ++t) {
            float a = sa[t];
            float dist = 1.0f - integ;      // dist_completion from OLD integrate
            float ii = integ + a;           // integrate += alpha
            bool fire = (ii >= THRESH);
            float cur = fire ? dist : a;
            ws[t] = cur;
            wn[t] = fire ? (a - cur) : 0.0f; // remainds, only meaningful at fires
            if (fire) {
                if (nf < LL) fp[nf] = t;
                nf++;
                ii = ii - 1.0f;
            }
            integ = ii;
        }
        nfires[b] = (nf < LL) ? nf : LL;
    }
}

__global__ __launch_bounds__(128) void cif_gather_kernel(
    const float* __restrict__ hidden,
    const float* __restrict__ w_self, const float* __restrict__ w_next,
    const int* __restrict__ fire_pos, const int* __restrict__ nfires,
    float* __restrict__ out)
{
    const int l = blockIdx.x;       // token index
    const int b = blockIdx.y;       // batch
    const int tid = threadIdx.x;    // 128 threads x float4 = 512 = HH

    float4 acc = make_float4(0.f, 0.f, 0.f, 0.f);
    const int F = nfires[b];
    if (l < F) {
        const int e = fire_pos[b * LL + l];          // fire step of this token
        const float* hb = hidden + (size_t)b * TT * HH + (size_t)tid * 4;
        const float* wsb = w_self + b * TT;
        int t0;
        if (l == 0) {
            t0 = 0;
        } else {
            const int sprev = fire_pos[b * LL + l - 1];
            const float w = w_next[b * TT + sprev];  // remainds seeds the new frame
            const float4 hv = *(const float4*)(hb + (size_t)sprev * HH);
            acc.x = w * hv.x; acc.y = w * hv.y; acc.z = w * hv.z; acc.w = w * hv.w;
            t0 = sprev + 1;
        }
        // Accumulate in ascending t, same order as the reference scan.
        for (int t = t0; t <= e; ++t) {
            const float w = wsb[t];                  // wave-uniform -> s_load
            const float4 hv = *(const float4*)(hb + (size_t)t * HH);
            acc.x += w * hv.x; acc.y += w * hv.y;
            acc.z += w * hv.z; acc.w += w * hv.w;
        }
    }
    *(float4*)(out + ((size_t)b * LL + l) * HH + (size_t)tid * 4) = acc;
}

extern "C" void kernel_launch(void* const* d_in, const int* in_sizes, int n_in,
                              void* d_out, int out_size, void* d_ws, size_t ws_size,
                              hipStream_t stream) {
    const float* hidden = (const float*)d_in[0];   // [B,T,H] f32
    const float* alphas = (const float*)d_in[1];   // [B,T]   f32
    const int*   tlen   = (const int*)d_in[2];     // [B]     i32
    float* out = (float*)d_out;                    // [B,L,H] f32

    float* w_self = (float*)d_ws;
    float* w_next = w_self + BB * TT;
    int* fire_pos = (int*)(w_next + BB * TT);
    int* nfires   = fire_pos + BB * LL;

    cif_scan_kernel<<<BB, 256, 0, stream>>>(alphas, tlen, w_self, w_next,
                                            fire_pos, nfires);
    cif_gather_kernel<<<dim3(LL, BB), 128, 0, stream>>>(hidden, w_self, w_next,
                                                        fire_pos, nfires, out);
}

// Round 2
// 300.263 us; speedup vs baseline: 1.1897x; 1.1897x over previous
//
#include <hip/hip_runtime.h>

#define BB 32
#define TT 2000
#define TTP 2048
#define HH 512
#define LL 256
#define THRESH 0.95f

// d_ws layout:
//   float w_self[BB*TT]   : per-step contribution to the currently-open token
//   float w_next[BB*TT]   : per-step contribution to the NEXT token (nonzero only at fires)
//   int   fire_pos[BB*LL] : time index of the l-th fire per batch
//   int   nfires[BB]      : number of fires (clamped to LL)

__global__ __launch_bounds__(256) void cif_scan_kernel(
    const float* __restrict__ alphas, const int* __restrict__ tlen,
    float* __restrict__ w_self, float* __restrict__ w_next,
    int* __restrict__ fire_pos, int* __restrict__ nfires)
{
    const int b = blockIdx.x;
    __shared__ float sa[TTP];
    __shared__ double red[256];

    const float* arow = alphas + b * TT;
    double s = 0.0;
    for (int t = threadIdx.x; t < TT; t += 256) {
        float a = arow[t];
        sa[t] = a;
        s += (double)a;
    }
    if (threadIdx.x < TTP - TT) sa[TT + threadIdx.x] = 0.0f;  // pad tail
    red[threadIdx.x] = s;
    __syncthreads();
    for (int off = 128; off > 0; off >>= 1) {
        if (threadIdx.x < off) red[threadIdx.x] += red[threadIdx.x + off];
        __syncthreads();
    }
    // Match reference: scale = float(target) / float(sum), f32 divide, f32 mult.
    const float sumf = (float)red[0];
    const float scale = (float)tlen[b] / sumf;
    for (int t = threadIdx.x; t < TT; t += 256) sa[t] = sa[t] * scale;
    __syncthreads();

    if (threadIdx.x == 0) {
        // Bit-exact f32 replay of the reference scan. Critical chain is only
        // ~12 cyc/step; keep LDS reads off it with a chunked register pipeline
        // (64 steps of compute per 16 ds_read_b128, next chunk prefetched).
        const float4* sa4 = (const float4*)sa;
        float4* ws4 = (float4*)(w_self + b * TT);
        float4* wn4 = (float4*)(w_next + b * TT);
        int* fp = fire_pos + b * LL;
        float integ = 0.0f;
        int nf = 0;

        float4 buf[16];
        #pragma unroll
        for (int i = 0; i < 16; ++i) buf[i] = sa4[i];

        for (int c = 0; c < 32; ++c) {
            float4 nbuf[16];
            if (c < 31) {
                #pragma unroll
                for (int i = 0; i < 16; ++i) nbuf[i] = sa4[(c + 1) * 16 + i];
            }
            #pragma unroll
            for (int i = 0; i < 16; ++i) {
                const int g = c * 16 + i;          // float4 group index (step 4g)
                if (g < TT / 4) {
                    const float av[4] = {buf[i].x, buf[i].y, buf[i].z, buf[i].w};
                    float wsv[4], wnv[4];
                    #pragma unroll
                    for (int j = 0; j < 4; ++j) {
                        const float a = av[j];
                        const float dist = 1.0f - integ;   // from OLD integrate
                        float ii = integ + a;              // integrate += alpha
                        const bool fire = (ii >= THRESH);
                        wsv[j] = fire ? dist : a;
                        wnv[j] = fire ? (a - wsv[j]) : 0.0f;
                        if (fire) {
                            if (nf < LL) fp[nf] = g * 4 + j;
                            nf++;
                            ii -= 1.0f;
                        }
                        integ = ii;
                    }
                    ws4[g] = make_float4(wsv[0], wsv[1], wsv[2], wsv[3]);
                    wn4[g] = make_float4(wnv[0], wnv[1], wnv[2], wnv[3]);
                }
            }
            #pragma unroll
            for (int i = 0; i < 16; ++i) buf[i] = nbuf[i];
        }
        nfires[b] = (nf < LL) ? nf : LL;
    }
}

__global__ __launch_bounds__(128) void cif_gather_kernel(
    const float* __restrict__ hidden,
    const float* __restrict__ w_self, const float* __restrict__ w_next,
    const int* __restrict__ fire_pos, const int* __restrict__ nfires,
    float* __restrict__ out)
{
    const int l = blockIdx.x;       // token index
    const int b = blockIdx.y;       // batch
    const int tid = threadIdx.x;    // 128 threads x float4 = 512 = HH

    float4 acc = make_float4(0.f, 0.f, 0.f, 0.f);
    const int F = nfires[b];
    if (l < F) {
        const int e = fire_pos[b * LL + l];          // fire step of this token
        const float* hb = hidden + (size_t)b * TT * HH + (size_t)tid * 4;
        const float* wsb = w_self + b * TT;
        int t0;
        if (l == 0) {
            t0 = 0;
        } else {
            const int sprev = fire_pos[b * LL + l - 1];
            const float w = w_next[b * TT + sprev];  // remainds seeds the new frame
            const float4 hv0 = *(const float4*)(hb + (size_t)sprev * HH);
            acc.x = w * hv0.x; acc.y = w * hv0.y; acc.z = w * hv0.z; acc.w = w * hv0.w;
            t0 = sprev + 1;
        }
        // Depth-1 software pipeline: next frame's load is issued before the
        // accumulate that waits on the current frame (no loop-carried vmcnt(0)).
        int t = t0;
        float w = wsb[t];
        float4 hv = *(const float4*)(hb + (size_t)t * HH);
        while (t < e) {
            const float wN = wsb[t + 1];
            const float4 hN = *(const float4*)(hb + (size_t)(t + 1) * HH);
            acc.x += w * hv.x; acc.y += w * hv.y;
            acc.z += w * hv.z; acc.w += w * hv.w;
            w = wN; hv = hN; ++t;
        }
        acc.x += w * hv.x; acc.y += w * hv.y;
        acc.z += w * hv.z; acc.w += w * hv.w;
    }
    *(float4*)(out + ((size_t)b * LL + l) * HH + (size_t)tid * 4) = acc;
}

extern "C" void kernel_launch(void* const* d_in, const int* in_sizes, int n_in,
                              void* d_out, int out_size, void* d_ws, size_t ws_size,
                              hipStream_t stream) {
    const float* hidden = (const float*)d_in[0];   // [B,T,H] f32
    const float* alphas = (const float*)d_in[1];   // [B,T]   f32
    const int*   tlen   = (const int*)d_in[2];     // [B]     i32
    float* out = (float*)d_out;                    // [B,L,H] f32

    float* w_self = (float*)d_ws;
    float* w_next = w_self + BB * TT;
    int* fire_pos = (int*)(w_next + BB * TT);
    int* nfires   = fire_pos + BB * LL;

    cif_scan_kernel<<<BB, 256, 0, stream>>>(alphas, tlen, w_self, w_next,
                                            fire_pos, nfires);
    cif_gather_kernel<<<dim3(LL, BB), 128, 0, stream>>>(hidden, w_self, w_next,
                                                        fire_pos, nfires, out);
}